// Round 3
// baseline (353.276 us; speedup 1.0000x reference)
//
#include <hip/hip_runtime.h>

// Grouped 1x7 conv (NCHW, N=128 C=24 H=W=112, groups=2, pad W=(3,3)) + roll(+1,H).
// out[n,o,(h+1)%112,w] = sum_{i,t} x[n, g*12+i, h, w+t-3] * wgt[i, o%12, t], g=o/12.
//
// One block per (n,h). Stage the 24 input rows into LDS with 4-float zero pads
// at both W edges (no bounds checks, ds_read_b128 with immediate-style offsets),
// and the 1008 weights re-laid-out to [ic][oc][8] for aligned b128 reads.
// Thread = 3 oc x 4 w = 12 accumulators (small enough that the compiler has no
// incentive to interchange loops / re-load x, which is what crippled round 1).

#define CHS 12544            // 112*112 floats per (n,c) plane
#define ROWP 120             // padded LDS row: 4 zero | 112 data | 4 zero

__global__ __launch_bounds__(256, 8) void conv1x7_lds(
    const float* __restrict__ x,
    const float* __restrict__ wgt,   // [12][12][7] : [ic][oc_local][tap]
    float* __restrict__ out)
{
    __shared__ float xs[24 * ROWP];   // 11520 B
    __shared__ float ws[12 * 12 * 8]; // 4608 B, [ic][oc][8]

    const int b   = blockIdx.x;       // 128*112 = 14336 blocks
    const int n   = b / 112;
    const int h   = b % 112;
    const int tid = threadIdx.x;

    // ---- stage x: 24 rows x 112 floats = 672 float4, coalesced ----
    const float* xrow = x + (size_t)n * 24 * CHS + h * 112;
    #pragma unroll
    for (int j0 = 0; j0 < 3; ++j0) {
        int j = j0 * 256 + tid;                   // 0..767, guard at 672
        if (j < 672) {
            int c  = j / 28;
            int wq = j % 28;
            float4 v = *reinterpret_cast<const float4*>(xrow + (size_t)c * CHS + wq * 4);
            *reinterpret_cast<float4*>(&xs[c * ROWP + 4 + wq * 4]) = v;
        }
    }
    // zero the W-edge pads: 24 rows x 2 float4
    if (tid < 48) {
        int c   = tid >> 1;
        int off = (tid & 1) ? 116 : 0;
        *reinterpret_cast<float4*>(&xs[c * ROWP + off]) = make_float4(0.f, 0.f, 0.f, 0.f);
    }
    // ---- stage weights, re-layout [ic][oc][7] -> [ic][oc][8] ----
    #pragma unroll
    for (int j0 = 0; j0 < 4; ++j0) {
        int j = j0 * 256 + tid;                   // 0..1023, guard at 1008
        if (j < 1008) {
            int ic = j / 84, r = j % 84;
            int oc = r / 7,  t = r % 7;
            ws[ic * 96 + oc * 8 + t] = wgt[j];
        }
    }
    __syncthreads();

    // ---- compute: ocset = tid>>5 (8 sets of 3 oc), q = tid&31 (w-quad) ----
    const int ocset = tid >> 5;
    const int q     = tid & 31;          // 28 active, 4 idle per set
    const int g     = ocset >> 2;        // group 0/1
    const int oc0   = ocset * 3;         // global out channel base (includes group)
    const int ocl0  = oc0 - g * 12;      // oc local to group, for weights

    if (q < 28) {
        float acc[3][4];
        #pragma unroll
        for (int j = 0; j < 3; ++j)
            #pragma unroll
            for (int p = 0; p < 4; ++p) acc[j][p] = 0.f;

        #pragma unroll
        for (int ic = 0; ic < 12; ++ic) {
            const float* xr = &xs[(g * 12 + ic) * ROWP + 4 * q];  // float idx of w0-4
            float4 xa = *reinterpret_cast<const float4*>(xr);
            float4 xb = *reinterpret_cast<const float4*>(xr + 4);
            float4 xc = *reinterpret_cast<const float4*>(xr + 8);
            float xv[12] = {xa.x, xa.y, xa.z, xa.w,
                            xb.x, xb.y, xb.z, xb.w,
                            xc.x, xc.y, xc.z, xc.w};
            #pragma unroll
            for (int j = 0; j < 3; ++j) {
                const float* wr = &ws[ic * 96 + (ocl0 + j) * 8];
                float4 wa = *reinterpret_cast<const float4*>(wr);
                float4 wb = *reinterpret_cast<const float4*>(wr + 4); // .w unused
                float wv[7] = {wa.x, wa.y, wa.z, wa.w, wb.x, wb.y, wb.z};
                #pragma unroll
                for (int t = 0; t < 7; ++t)
                    #pragma unroll
                    for (int p = 0; p < 4; ++p)
                        acc[j][p] = fmaf(xv[1 + t + p], wv[t], acc[j][p]);
            }
        }

        int ho = h + 1; if (ho == 112) ho = 0;     // roll(+1) on H
        float* ob = out + (size_t)(n * 24 + oc0) * CHS + ho * 112 + 4 * q;
        #pragma unroll
        for (int j = 0; j < 3; ++j) {
            *reinterpret_cast<float4*>(ob + (size_t)j * CHS) =
                make_float4(acc[j][0], acc[j][1], acc[j][2], acc[j][3]);
        }
    }
}

extern "C" void kernel_launch(void* const* d_in, const int* in_sizes, int n_in,
                              void* d_out, int out_size, void* d_ws, size_t ws_size,
                              hipStream_t stream)
{
    const float* x = (const float*)d_in[0];   // 128*24*112*112
    const float* w = (const float*)d_in[1];   // 12*12*7
    float* out = (float*)d_out;

    dim3 grid(128 * 112), block(256);
    hipLaunchKernelGGL(conv1x7_lds, grid, block, 0, stream, x, w, out);
}

// Round 4
// 290.858 us; speedup vs baseline: 1.2146x; 1.2146x over previous
//
#include <hip/hip_runtime.h>

// Grouped 1x7 conv (NCHW, N=128 C=24 H=W=112, groups=2, pad W=(3,3)) + roll(+1,H),
// fp32. out[n, g*12+o, (h+1)%112, w] = sum_{i,t} x[n, g*12+i, h, w+t-3] * w[i,o,t].
//
// Round-3 lesson: LDS pipe was the bottleneck (4.7e7 conflict cycles, x re-read 4x).
// This version uses NO LDS. Thread = 12 oc x 4 px (48 acc); x read once per thread
// as 3 float4 global loads per ic (adjacent lanes' overlapping windows hit L1).
// Weights are repacked tap-major [ic][tap][oc=12] into d_ws by a prep kernel so the
// main loop reads them as 3 float4s from a wave-uniform address (s_load / broadcast).
// 448-thread blocks (7 waves) = 8 rows x 56 threads: zero idle lanes.

#define CHS 12544   // 112*112

__global__ void prep_w(const float* __restrict__ wgt, float* __restrict__ wT) {
    int j = blockIdx.x * 256 + threadIdx.x;           // 1008 weights
    if (j < 1008) {
        int ic = j / 84, r = j % 84;
        int oc = r / 7,  t = r % 7;
        wT[(ic * 7 + t) * 12 + oc] = wgt[j];          // [ic][tap][oc]
    }
}

__global__ __launch_bounds__(448) void conv1x7_reg(
    const float* __restrict__ x,
    const float* __restrict__ wT,    // [12][7][12] tap-major
    float* __restrict__ out)
{
    const int t448  = threadIdx.x;            // 0..447
    const int rowid = blockIdx.x * 8 + t448 / 56;   // (n,h) row, 14336 total
    const int l56   = t448 % 56;
    const int n = rowid / 112;
    const int h = rowid % 112;
    const int g = l56 / 28;                   // group
    const int q = l56 % 28;                   // w-quad
    const int w0 = q * 4;

    const float* xrow = x + ((size_t)(n * 24 + g * 12) * 112 + h) * 112;

    const bool q0  = (q == 0);
    const bool q27 = (q == 27);
    const int offA = q0  ? 0   : (w0 - 4);    // clamped, always in-bounds
    const int offC = q27 ? 108 : (w0 + 4);

    float acc[12][4];
    #pragma unroll
    for (int o = 0; o < 12; ++o)
        acc[o][0] = acc[o][1] = acc[o][2] = acc[o][3] = 0.f;

    #pragma unroll 2
    for (int ic = 0; ic < 12; ++ic) {
        const float* xr = xrow + (size_t)ic * CHS;
        float4 xa = *reinterpret_cast<const float4*>(xr + offA);
        float4 xb = *reinterpret_cast<const float4*>(xr + w0);
        float4 xc = *reinterpret_cast<const float4*>(xr + offC);
        if (q0)  xa = make_float4(0.f, 0.f, 0.f, 0.f);   // w = -4..-1 -> zero pad
        if (q27) xc = make_float4(0.f, 0.f, 0.f, 0.f);   // w = 112..115 -> zero pad
        const float xv[12] = {xa.x, xa.y, xa.z, xa.w,
                              xb.x, xb.y, xb.z, xb.w,
                              xc.x, xc.y, xc.z, xc.w};
        const float* wr = wT + ic * 84;       // wave-uniform
        #pragma unroll
        for (int t = 0; t < 7; ++t) {
            float4 wA = *reinterpret_cast<const float4*>(wr + t * 12);
            float4 wB = *reinterpret_cast<const float4*>(wr + t * 12 + 4);
            float4 wC = *reinterpret_cast<const float4*>(wr + t * 12 + 8);
            const float wv[12] = {wA.x, wA.y, wA.z, wA.w,
                                  wB.x, wB.y, wB.z, wB.w,
                                  wC.x, wC.y, wC.z, wC.w};
            #pragma unroll
            for (int o = 0; o < 12; ++o)
                #pragma unroll
                for (int p = 0; p < 4; ++p)
                    acc[o][p] = fmaf(xv[1 + t + p], wv[o], acc[o][p]);
        }
    }

    int ho = h + 1; if (ho == 112) ho = 0;    // roll(+1) on H
    float* ob = out + ((size_t)(n * 24 + g * 12) * 112 + ho) * 112 + w0;
    #pragma unroll
    for (int o = 0; o < 12; ++o)
        *reinterpret_cast<float4*>(ob + (size_t)o * CHS) =
            make_float4(acc[o][0], acc[o][1], acc[o][2], acc[o][3]);
}

extern "C" void kernel_launch(void* const* d_in, const int* in_sizes, int n_in,
                              void* d_out, int out_size, void* d_ws, size_t ws_size,
                              hipStream_t stream)
{
    const float* x = (const float*)d_in[0];   // 128*24*112*112
    const float* w = (const float*)d_in[1];   // 12*12*7
    float* out = (float*)d_out;
    float* wT  = (float*)d_ws;                // 1008 floats = 4032 B

    hipLaunchKernelGGL(prep_w, dim3(4), dim3(256), 0, stream, w, wT);
    // 14336 rows / 8 rows per block = 1792 blocks of 448 threads (7 waves, no idle lanes)
    hipLaunchKernelGGL(conv1x7_reg, dim3(1792), dim3(448), 0, stream, x, wT, out);
}